// Round 10
// baseline (27459.146 us; speedup 1.0000x reference)
//
#include <hip/hip_runtime.h>

#define HDIM 96
#define G4   384
#define LSEQ 32768
#define BATCH 8
#define TCH   1024
#define NCH   (LSEQ / TCH)

#define L2E  1.4426950408889634f
#define SNEG (-L2E)        /* sigmoid gates: exp(-x) = exp2(SNEG*x) */
#define SPOS (2.0f * L2E)  /* tanh gates:    exp(2x) = exp2(SPOS*x) */

__device__ __forceinline__ float tanh_(float x) {    // raw argument (c state)
    // overflow-safe: exp2 -> inf => rcp -> 0 => tanh -> 1. NO fused form here.
    return fmaf(-2.f, __builtin_amdgcn_rcpf(1.f + __builtin_amdgcn_exp2f(SPOS * x)), 1.f);
}

// DPP helpers (VALU pipe, zero DS usage).
#define DPPSTEP(v, CTRL) { \
    int t_ = __builtin_amdgcn_update_dpp(0, __float_as_int(v), CTRL, 0xF, 0xF, true); \
    v += __int_as_float(t_); }
#define DPPADDV(u, v, CTRL) { \
    int t_ = __builtin_amdgcn_update_dpp(0, __float_as_int(v), CTRL, 0xF, 0xF, true); \
    u += __int_as_float(t_); }

// quad_perm broadcast: all lanes of each quad read quad-lane L of src.
#define QBCAST(DST, SRCI, CTRL) \
    float DST = __int_as_float(__builtin_amdgcn_update_dpp(0, (SRCI), (CTRL), 0xF, 0xF, true));

// Lite barrier: LDS ordering only; global ops stay in flight.
#define BARL() asm volatile("s_waitcnt lgkmcnt(0)\n\ts_barrier" ::: "memory")

#define PIN4x3(A,B,C) asm volatile("" : \
  "+v"(A.x),"+v"(A.y),"+v"(A.z),"+v"(A.w), \
  "+v"(B.x),"+v"(B.y),"+v"(B.z),"+v"(B.w), \
  "+v"(C.x),"+v"(C.y),"+v"(C.z),"+v"(C.w));

#define SC4(V, S) { V.x *= (S); V.y *= (S); V.z *= (S); V.w *= (S); }

// Thread owns all 4 gate rows of element e x cols [12s, 12s+12).
// Weights pre-scaled per gate for exp2-direct activations; SHARED by both
// sequences in the block (same 48 VGPRs — that is the point of pairing).
#define WLOADPIN(W) \
    const float4* pI = reinterpret_cast<const float4*>((W) + (size_t)e        * HDIM + 12*s); \
    const float4* pF = reinterpret_cast<const float4*>((W) + (size_t)(96 + e) * HDIM + 12*s); \
    const float4* pG = reinterpret_cast<const float4*>((W) + (size_t)(192+ e) * HDIM + 12*s); \
    const float4* pO = reinterpret_cast<const float4*>((W) + (size_t)(288+ e) * HDIM + 12*s); \
    float4 wI0=pI[0], wI1=pI[1], wI2=pI[2]; \
    float4 wF0=pF[0], wF1=pF[1], wF2=pF[2]; \
    float4 wG0=pG[0], wG1=pG[1], wG2=pG[2]; \
    float4 wO0=pO[0], wO1=pO[1], wO2=pO[2]; \
    SC4(wI0,SNEG) SC4(wI1,SNEG) SC4(wI2,SNEG) \
    SC4(wF0,SNEG) SC4(wF1,SNEG) SC4(wF2,SNEG) \
    SC4(wG0,SPOS) SC4(wG1,SPOS) SC4(wG2,SPOS) \
    SC4(wO0,SNEG) SC4(wO1,SNEG) SC4(wO2,SNEG) \
    PIN4x3(wI0,wI1,wI2) PIN4x3(wF0,wF1,wF2) PIN4x3(wG0,wG1,wG2) PIN4x3(wO0,wO1,wO2)

#define MVK(n, hv) \
  gi=fmaf(wI##n.x,hv.x,gi); gi=fmaf(wI##n.y,hv.y,gi); gi=fmaf(wI##n.z,hv.z,gi); gi=fmaf(wI##n.w,hv.w,gi); \
  gf=fmaf(wF##n.x,hv.x,gf); gf=fmaf(wF##n.y,hv.y,gf); gf=fmaf(wF##n.z,hv.z,gf); gf=fmaf(wF##n.w,hv.w,gf); \
  gg=fmaf(wG##n.x,hv.x,gg); gg=fmaf(wG##n.y,hv.y,gg); gg=fmaf(wG##n.z,hv.z,gg); gg=fmaf(wG##n.w,hv.w,gg); \
  go=fmaf(wO##n.x,hv.x,go); go=fmaf(wO##n.y,hv.y,go); go=fmaf(wO##n.z,hv.z,go); go=fmaf(wO##n.w,hv.w,go);

// Merged transposing reduction + batched activation tail, MIRROR-SYMMETRIC
// (verified bitwise-identical to RED8 in R9). Parametrized on the cell
// state variable so two sequences can share the macro.
#define GATES_TAILX(CUV, DEST_STORE) \
    float uA = (tsel & 1) ? gf : gi,  vA = (tsel & 1) ? gi : gf; \
    float uB = (tsel & 1) ? go : gg,  vB = (tsel & 1) ? gg : go; \
    DPPADDV(uA, vA, 0xB1)  DPPADDV(uB, vB, 0xB1) \
    float uC = (tsel & 2) ? uB : uA,  vC = (tsel & 2) ? uA : uB; \
    DPPADDV(uC, vC, 0x4E) \
    DPPSTEP(uC, 0x141) \
    float E_ = __builtin_amdgcn_exp2f(uC); \
    float r_ = __builtin_amdgcn_rcpf(1.f + E_); \
    int ai = __float_as_int(fmaf(mC, r_, aC)); \
    QBCAST(si, ai, 0x00) \
    QBCAST(sf, ai, 0x55) \
    QBCAST(tg, ai, 0xAA) \
    QBCAST(so, ai, 0xFF) \
    CUV = fmaf(sf, CUV, si * tg); \
    float hN = so * tanh_(CUV); \
    DEST_STORE

// One LSTM step, role 0, sequence-parametrized. BASE = 0 (seq A) or 192
// (seq B) into hs2; OFF = 0/HDIM double-buffer toggle (compile-time).
#define STEP0X(BASE, OFF, XT, CUV, HOBP) { \
    const float4* hp = reinterpret_cast<const float4*>(hs2 + (BASE) + (OFF) + 12 * s); \
    float4 hv0 = hp[0], hv1 = hp[1], hv2 = hp[2]; \
    float gi = fmaf(wiI, (XT), bbI); \
    float gf = fmaf(wiF, (XT), bbF); \
    float gg = fmaf(wiG, (XT), bbG); \
    float go = fmaf(wiO, (XT), bbO); \
    MVK(0, hv0) MVK(1, hv1) MVK(2, hv2) \
    GATES_TAILX(CUV, \
      if (w0l) { hs2[(BASE) + ((OFF) ^ HDIM) + e] = hN; *(HOBP) = hN; } \
      (HOBP) += HDIM; ) }

// One LSTM step, role 2, sequence-parametrized. xp pre-scaled at role 1.
#define STEP2X(BASE, OFF, XPV, CUV, H1P) { \
    const float4* hp = reinterpret_cast<const float4*>(hs2 + (BASE) + (OFF) + 12 * s); \
    float4 hv0 = hp[0], hv1 = hp[1], hv2 = hp[2]; \
    float gi = (XPV).x, gf = (XPV).y, gg = (XPV).z, go = (XPV).w; \
    MVK(0, hv0) MVK(1, hv1) MVK(2, hv2) \
    GATES_TAILX(CUV, \
      if (w0l) { hs2[(BASE) + ((OFF) ^ HDIM) + e] = hN; *(H1P) = hN; } \
      (H1P) += HDIM; ) }

#define WAIT_GE(PTR, VAL) \
    while (__hip_atomic_load((PTR), __ATOMIC_ACQUIRE, __HIP_MEMORY_SCOPE_AGENT) < (VAL)) \
        __builtin_amdgcn_s_sleep(2);

#define SIGNAL(PTR, VAL) \
    __hip_atomic_store((PTR), (VAL), __ATOMIC_RELEASE, __HIP_MEMORY_SCOPE_AGENT);

__global__ void init_flags(int* flags) {
    if (threadIdx.x < 64) flags[threadIdx.x] = 0;
}

// ---------------------------------------------------------------------------
// 16 blocks, 4 roles x 4 pair-blocks. Pair pr = blockIdx&3 handles batches
// bA=2pr, bB=2pr+1. TWO independent recurrences per scan block: their
// issue streams fill each other's latency stalls (R9 showed ~390 cyc/step
// of un-hideable chain latency with one sequence). Weights shared in VGPRs.
// Flags are per-pair: both batches' chunks complete at the same barrier.
//   role 0: dual L0 scan -> h0buf, flag0[pr]
//   role 1: xp worker, both batches per chunk -> xp ring, flag1[pr]
//   role 2: dual L1 scan -> h1 ring, flag2[pr]
//   role 3: head, both batches -> out, flag3[pr]
// ---------------------------------------------------------------------------
__global__ void __launch_bounds__(768)
__attribute__((amdgpu_waves_per_eu(3, 3)))
lstm_pipe(const float* __restrict__ x,
          const float* __restrict__ Wih0, const float* __restrict__ Whh0, const float* __restrict__ b0v,
          const float* __restrict__ Wih1, const float* __restrict__ Whh1, const float* __restrict__ b1v,
          const float* __restrict__ h0v,  const float* __restrict__ c0v,
          const float* __restrict__ headw,const float* __restrict__ headb,
          float* __restrict__ h0buf, float* __restrict__ xpbuf, float* __restrict__ h1buf,
          int* flags, float* __restrict__ out)
{
    const int tid  = threadIdx.x;
    const int lane = tid & 63;
    const int e    = tid >> 3;     // element 0..95
    const int s    = tid & 7;      // 12-col segment 0..7
    const bool w0l = ((lane & 7) == 0);

    int* flag0 = flags;
    int* flag1 = flags + 8;
    int* flag2 = flags + 16;
    int* flag3 = flags + 24;

    __shared__ __align__(16) float hs2[2 * 2 * HDIM];   // [seq][dbuf][96]
    __shared__ __align__(16) float h_sh[32 * HDIM];
    __shared__ float ph_sh[2 * G4];          // tt-parity double buffer

    const int role = blockIdx.x >> 2;
    const int pr   = blockIdx.x & 3;
    const int bA   = 2 * pr;
    const int bB   = 2 * pr + 1;

    // mirror-symmetric gate index for the merged butterfly (loop-invariant):
    // quad 0 -> i,f,g,o ; quad 1 -> o,g,f,i
    const int tsel = (s & 3) ^ ((s & 4) ? 3 : 0);
    const float mC = (tsel == 2) ? -2.f : 1.f;
    const float aC = (tsel == 2) ?  1.f : 0.f;

    if (role == 0) {
        // =================== producer: dual L0 scan ===================
        WLOADPIN(Whh0)
        // input weights + bias pre-scaled by gate-const and 1/8 (butterfly
        // sums 8 identical copies back to full value — exact). Shared.
        const float wiI = Wih0[e]      * (SNEG * 0.125f);
        const float wiF = Wih0[96 + e] * (SNEG * 0.125f);
        const float wiG = Wih0[192+ e] * (SPOS * 0.125f);
        const float wiO = Wih0[288+ e] * (SNEG * 0.125f);
        const float bbI = b0v[e]       * (SNEG * 0.125f);
        const float bbF = b0v[96 + e]  * (SNEG * 0.125f);
        const float bbG = b0v[192+ e]  * (SPOS * 0.125f);
        const float bbO = b0v[288+ e]  * (SNEG * 0.125f);

        float cUA = c0v[e], cUB = c0v[e];
        if (w0l) { hs2[e] = h0v[e]; hs2[192 + e] = h0v[e]; }
        __syncthreads();

        const float* xbA = x + (size_t)bA * LSEQ;
        const float* xbB = x + (size_t)bB * LSEQ;
        float* hobpA = h0buf + (size_t)bA * LSEQ * HDIM + e;
        float* hobpB = h0buf + (size_t)bB * LSEQ * HDIM + e;

        float4 xAA = *reinterpret_cast<const float4*>(xbA);   // t = 0..3
        float4 xAB = *reinterpret_cast<const float4*>(xbB);

#pragma unroll 1
        for (int gI = 0; gI < LSEQ / 8; ++gI) {
            float4 xBA = *reinterpret_cast<const float4*>(xbA + gI * 8 + 4);
            float4 xBB = *reinterpret_cast<const float4*>(xbB + gI * 8 + 4);
            STEP0X(0,  0,    xAA.x, cUA, hobpA) STEP0X(192, 0,    xAB.x, cUB, hobpB) BARL();
            STEP0X(0,  HDIM, xAA.y, cUA, hobpA) STEP0X(192, HDIM, xAB.y, cUB, hobpB) BARL();
            STEP0X(0,  0,    xAA.z, cUA, hobpA) STEP0X(192, 0,    xAB.z, cUB, hobpB) BARL();
            STEP0X(0,  HDIM, xAA.w, cUA, hobpA) STEP0X(192, HDIM, xAB.w, cUB, hobpB) BARL();
            const int nOff = ((gI + 1) * 8 < LSEQ) ? (gI + 1) * 8 : LSEQ - 8;
            float4 xAnA = *reinterpret_cast<const float4*>(xbA + nOff);
            float4 xAnB = *reinterpret_cast<const float4*>(xbB + nOff);
            STEP0X(0,  0,    xBA.x, cUA, hobpA) STEP0X(192, 0,    xBB.x, cUB, hobpB) BARL();
            STEP0X(0,  HDIM, xBA.y, cUA, hobpA) STEP0X(192, HDIM, xBB.y, cUB, hobpB) BARL();
            STEP0X(0,  0,    xBA.z, cUA, hobpA) STEP0X(192, 0,    xBB.z, cUB, hobpB) BARL();
            STEP0X(0,  HDIM, xBA.w, cUA, hobpA) STEP0X(192, HDIM, xBB.w, cUB, hobpB)
            xAA = xAnA; xAB = xAnB;
            if (((gI + 1) & 127) == 0) {      // t+1 = 8(gI+1) ≡ 0 mod TCH
                __threadfence();
                __syncthreads();
                if (tid == 0) SIGNAL(&flag0[pr], (gI + 1) >> 7)
            } else {
                BARL();
            }
        }
    } else if (role == 1) {
        // =================== xp worker (both batches/chunk) ===============
        const bool halfx = (tid >= G4);
        const int  g     = halfx ? tid - G4 : tid;
        const int  dstoff = (g % 96) * 4 + (g / 96);   // (e,gate) float4 layout
        const float gsc  = (((g / 96) == 2) ? SPOS : SNEG) * 0.125f;
        const float4* Wxp = reinterpret_cast<const float4*>(Wih1 + (size_t)g * HDIM + (halfx ? 48 : 0));
        const float xbias = halfx ? 0.f : b1v[g] * gsc;

        float4 q0=Wxp[0],q1=Wxp[1],q2=Wxp[2],q3=Wxp[3],q4=Wxp[4],q5=Wxp[5],
               q6=Wxp[6],q7=Wxp[7],q8=Wxp[8],q9=Wxp[9],q10=Wxp[10],q11=Wxp[11];
        SC4(q0,gsc) SC4(q1,gsc) SC4(q2,gsc)  SC4(q3,gsc) SC4(q4,gsc)  SC4(q5,gsc)
        SC4(q6,gsc) SC4(q7,gsc) SC4(q8,gsc)  SC4(q9,gsc) SC4(q10,gsc) SC4(q11,gsc)
        PIN4x3(q0,q1,q2) PIN4x3(q3,q4,q5) PIN4x3(q6,q7,q8) PIN4x3(q9,q10,q11)

#pragma unroll 1
        for (int k = 0; k < NCH; ++k) {
            if (tid == 0) {
                WAIT_GE(&flag0[pr], k + 1)
                if (k >= 2) WAIT_GE(&flag2[pr], k - 1)
            }
            __syncthreads();
            __threadfence();

#pragma unroll 1
            for (int bb = 0; bb < 2; ++bb) {
                const int b = 2 * pr + bb;
                const float* hsrc = h0buf + (size_t)b * LSEQ * HDIM + (size_t)k * TCH * HDIM;
                float* xpd = xpbuf + ((size_t)b * 2 + (k & 1)) * TCH * G4;

#pragma unroll 1
                for (int t0 = 0; t0 < TCH; t0 += 32) {
                    // 32*96 floats = exactly one float4 per thread
                    reinterpret_cast<float4*>(h_sh)[tid] =
                        reinterpret_cast<const float4*>(hsrc + (size_t)t0 * HDIM)[tid];
                    BARL();
#pragma unroll 1
                    for (int tt = 0; tt < 32; ++tt) {
                        const float4* h4 = reinterpret_cast<const float4*>(
                            h_sh + tt * HDIM + (halfx ? 48 : 0));
                        float a0 = xbias, a1 = 0.f, a2 = 0.f, a3 = 0.f;
                        float4 hv;
                        hv=h4[0];  a0=fmaf(q0.x, hv.x,a0); a1=fmaf(q0.y, hv.y,a1); a2=fmaf(q0.z, hv.z,a2); a3=fmaf(q0.w, hv.w,a3);
                        hv=h4[1];  a0=fmaf(q1.x, hv.x,a0); a1=fmaf(q1.y, hv.y,a1); a2=fmaf(q1.z, hv.z,a2); a3=fmaf(q1.w, hv.w,a3);
                        hv=h4[2];  a0=fmaf(q2.x, hv.x,a0); a1=fmaf(q2.y, hv.y,a1); a2=fmaf(q2.z, hv.z,a2); a3=fmaf(q2.w, hv.w,a3);
                        hv=h4[3];  a0=fmaf(q3.x, hv.x,a0); a1=fmaf(q3.y, hv.y,a1); a2=fmaf(q3.z, hv.z,a2); a3=fmaf(q3.w, hv.w,a3);
                        hv=h4[4];  a0=fmaf(q4.x, hv.x,a0); a1=fmaf(q4.y, hv.y,a1); a2=fmaf(q4.z, hv.z,a2); a3=fmaf(q4.w, hv.w,a3);
                        hv=h4[5];  a0=fmaf(q5.x, hv.x,a0); a1=fmaf(q5.y, hv.y,a1); a2=fmaf(q5.z, hv.z,a2); a3=fmaf(q5.w, hv.w,a3);
                        hv=h4[6];  a0=fmaf(q6.x, hv.x,a0); a1=fmaf(q6.y, hv.y,a1); a2=fmaf(q6.z, hv.z,a2); a3=fmaf(q6.w, hv.w,a3);
                        hv=h4[7];  a0=fmaf(q7.x, hv.x,a0); a1=fmaf(q7.y, hv.y,a1); a2=fmaf(q7.z, hv.z,a2); a3=fmaf(q7.w, hv.w,a3);
                        hv=h4[8];  a0=fmaf(q8.x, hv.x,a0); a1=fmaf(q8.y, hv.y,a1); a2=fmaf(q8.z, hv.z,a2); a3=fmaf(q8.w, hv.w,a3);
                        hv=h4[9];  a0=fmaf(q9.x, hv.x,a0); a1=fmaf(q9.y, hv.y,a1); a2=fmaf(q9.z, hv.z,a2); a3=fmaf(q9.w, hv.w,a3);
                        hv=h4[10]; a0=fmaf(q10.x,hv.x,a0); a1=fmaf(q10.y,hv.y,a1); a2=fmaf(q10.z,hv.z,a2); a3=fmaf(q10.w,hv.w,a3);
                        hv=h4[11]; a0=fmaf(q11.x,hv.x,a0); a1=fmaf(q11.y,hv.y,a1); a2=fmaf(q11.z,hv.z,a2); a3=fmaf(q11.w,hv.w,a3);
                        float part = (a0 + a1) + (a2 + a3);
                        float* ph2 = ph_sh + ((tt & 1) ? G4 : 0);   // parity dbuf
                        if (halfx) ph2[g] = part;
                        BARL();
                        if (!halfx) xpd[(size_t)(t0 + tt) * G4 + dstoff] = part + ph2[g];
                    }
                    BARL();   // protect h_sh + ph slot reuse before next stage
                }
            }
            __threadfence();
            __syncthreads();
            if (tid == 0) SIGNAL(&flag1[pr], k + 1)
        }
    } else if (role == 2) {
        // =================== consumer: dual L1 scan ===================
        WLOADPIN(Whh1)

        float cUA = c0v[HDIM + e], cUB = c0v[HDIM + e];
        if (w0l) { hs2[e] = h0v[HDIM + e]; hs2[192 + e] = h0v[HDIM + e]; }
        __syncthreads();

#pragma unroll 1
        for (int k = 0; k < NCH; ++k) {
            if (tid == 0) {
                WAIT_GE(&flag1[pr], k + 1)
                if (k >= 2) WAIT_GE(&flag3[pr], k - 1)
            }
            __syncthreads();
            __threadfence();

            const float4* xqA = reinterpret_cast<const float4*>(
                xpbuf + ((size_t)bA * 2 + (k & 1)) * TCH * G4) + e;
            const float4* xqB = reinterpret_cast<const float4*>(
                xpbuf + ((size_t)bB * 2 + (k & 1)) * TCH * G4) + e;
            float* h1pA = h1buf + ((size_t)bA * 2 + (k & 1)) * TCH * HDIM + e;
            float* h1pB = h1buf + ((size_t)bB * 2 + (k & 1)) * TCH * HDIM + e;

            float4 aA0 = xqA[0], aA1 = xqA[HDIM], aA2 = xqA[2 * HDIM], aA3 = xqA[3 * HDIM];
            float4 aB0 = xqB[0], aB1 = xqB[HDIM], aB2 = xqB[2 * HDIM], aB3 = xqB[3 * HDIM];

#pragma unroll 1
            for (int gI = 0; gI < TCH / 8; ++gI) {
                const float4* xgA = xqA + (size_t)gI * 8 * HDIM;
                const float4* xgB = xqB + (size_t)gI * 8 * HDIM;
                float4 bA0_, bA1_, bA2_, bA3_, bB0_, bB1_, bB2_, bB3_;
                STEP2X(0,  0,    aA0, cUA, h1pA) STEP2X(192, 0,    aB0, cUB, h1pB)
                bA0_ = xgA[4 * HDIM]; bB0_ = xgB[4 * HDIM]; BARL();
                STEP2X(0,  HDIM, aA1, cUA, h1pA) STEP2X(192, HDIM, aB1, cUB, h1pB)
                bA1_ = xgA[5 * HDIM]; bB1_ = xgB[5 * HDIM]; BARL();
                STEP2X(0,  0,    aA2, cUA, h1pA) STEP2X(192, 0,    aB2, cUB, h1pB)
                bA2_ = xgA[6 * HDIM]; bB2_ = xgB[6 * HDIM]; BARL();
                STEP2X(0,  HDIM, aA3, cUA, h1pA) STEP2X(192, HDIM, aB3, cUB, h1pB)
                bA3_ = xgA[7 * HDIM]; bB3_ = xgB[7 * HDIM]; BARL();
                const size_t nO = (size_t)((gI + 1 < TCH / 8) ? (gI + 1) * 8 : TCH - 8) * HDIM;
                const float4* xnA = xqA + nO;
                const float4* xnB = xqB + nO;
                STEP2X(0,  0,    bA0_, cUA, h1pA) STEP2X(192, 0,    bB0_, cUB, h1pB)
                aA0 = xnA[0];        aB0 = xnB[0];        BARL();
                STEP2X(0,  HDIM, bA1_, cUA, h1pA) STEP2X(192, HDIM, bB1_, cUB, h1pB)
                aA1 = xnA[HDIM];     aB1 = xnB[HDIM];     BARL();
                STEP2X(0,  0,    bA2_, cUA, h1pA) STEP2X(192, 0,    bB2_, cUB, h1pB)
                aA2 = xnA[2 * HDIM]; aB2 = xnB[2 * HDIM]; BARL();
                STEP2X(0,  HDIM, bA3_, cUA, h1pA) STEP2X(192, HDIM, bB3_, cUB, h1pB)
                aA3 = xnA[3 * HDIM]; aB3 = xnB[3 * HDIM]; BARL();
            }
            __threadfence();
            __syncthreads();
            if (tid == 0) SIGNAL(&flag2[pr], k + 1)
        }
    } else {
        // =================== head (both batches/chunk) ===================
        const float hb = headb[0];
        float4 wv[24];
#pragma unroll
        for (int j = 0; j < 24; ++j) wv[j] = reinterpret_cast<const float4*>(headw)[j];

#pragma unroll 1
        for (int k = 0; k < NCH; ++k) {
            if (tid == 0) WAIT_GE(&flag2[pr], k + 1)
            __syncthreads();
            __threadfence();

#pragma unroll 1
            for (int bb = 0; bb < 2; ++bb) {
                const int b = 2 * pr + bb;
                const float* h1c = h1buf + ((size_t)b * 2 + (k & 1)) * TCH * HDIM;
                for (int t = tid; t < TCH; t += 768) {
                    const float4* hp = reinterpret_cast<const float4*>(h1c + (size_t)t * HDIM);
                    float s2 = 0.f;
#pragma unroll
                    for (int j = 0; j < 24; ++j) {
                        float4 a = hp[j], bwv = wv[j];
                        s2 = fmaf(a.x, bwv.x, s2); s2 = fmaf(a.y, bwv.y, s2);
                        s2 = fmaf(a.z, bwv.z, s2); s2 = fmaf(a.w, bwv.w, s2);
                    }
                    out[(size_t)b * LSEQ + (size_t)k * TCH + t] = s2 + hb;
                }
            }
            __threadfence();
            __syncthreads();
            if (tid == 0) SIGNAL(&flag3[pr], k + 1)
        }
    }
}

// ---------------------------------------------------------------------------
extern "C" void kernel_launch(void* const* d_in, const int* in_sizes, int n_in,
                              void* d_out, int out_size, void* d_ws, size_t ws_size,
                              hipStream_t stream)
{
    const float* x     = (const float*)d_in[0];
    const float* Wih0  = (const float*)d_in[1];
    const float* Whh0  = (const float*)d_in[2];
    const float* b0    = (const float*)d_in[3];
    const float* Wih1  = (const float*)d_in[4];
    const float* Whh1  = (const float*)d_in[5];
    const float* b1    = (const float*)d_in[6];
    const float* h0    = (const float*)d_in[7];
    const float* c0    = (const float*)d_in[8];
    const float* headw = (const float*)d_in[9];
    const float* headb = (const float*)d_in[10];
    float* out = (float*)d_out;

    char* ws = (char*)d_ws;
    const size_t h0bytes = (size_t)BATCH * LSEQ * HDIM * sizeof(float);    // 100.7 MB
    const size_t xpbytes = (size_t)BATCH * 2 * TCH * G4 * sizeof(float);   // 25.2 MB
    const size_t h1bytes = (size_t)BATCH * 2 * TCH * HDIM * sizeof(float); // 6.3 MB

    float* h0buf = (float*)ws;
    float* xpbuf = (float*)(ws + h0bytes);
    float* h1buf = (float*)(ws + h0bytes + xpbytes);
    int*   flags = (int*)  (ws + h0bytes + xpbytes + h1bytes);

    init_flags<<<1, 64, 0, stream>>>(flags);
    lstm_pipe<<<16, 768, 0, stream>>>(x, Wih0, Whh0, b0, Wih1, Whh1, b1,
                                      h0, c0, headw, headb,
                                      h0buf, xpbuf, h1buf, flags, out);
}

// Round 11
// 26568.140 us; speedup vs baseline: 1.0335x; 1.0335x over previous
//
#include <hip/hip_runtime.h>

#define HDIM 96
#define G4   384
#define LSEQ 32768
#define BATCH 8
#define TCH   1024
#define NCH   (LSEQ / TCH)

#define L2E  1.4426950408889634f
#define SNEG (-L2E)        /* sigmoid gates: exp(-x) = exp2(SNEG*x) */
#define SPOS (2.0f * L2E)  /* tanh gates:    exp(2x) = exp2(SPOS*x) */

// DPP helpers (VALU pipe, zero DS usage).
#define DPPSTEP(v, CTRL) { \
    int t_ = __builtin_amdgcn_update_dpp(0, __float_as_int(v), CTRL, 0xF, 0xF, true); \
    v += __int_as_float(t_); }
#define DPPADDV(u, v, CTRL) { \
    int t_ = __builtin_amdgcn_update_dpp(0, __float_as_int(v), CTRL, 0xF, 0xF, true); \
    u += __int_as_float(t_); }

// quad_perm broadcast: all lanes of each quad read quad-lane L of src.
#define QBCAST(DST, SRCI, CTRL) \
    float DST = __int_as_float(__builtin_amdgcn_update_dpp(0, (SRCI), (CTRL), 0xF, 0xF, true));

// Lite barrier: LDS ordering only; global ops stay in flight.
#define BARL() asm volatile("s_waitcnt lgkmcnt(0)\n\ts_barrier" ::: "memory")

#define PIN4x3(A,B,C) asm volatile("" : \
  "+v"(A.x),"+v"(A.y),"+v"(A.z),"+v"(A.w), \
  "+v"(B.x),"+v"(B.y),"+v"(B.z),"+v"(B.w), \
  "+v"(C.x),"+v"(C.y),"+v"(C.z),"+v"(C.w));

#define SC4(V, S) { V.x *= (S); V.y *= (S); V.z *= (S); V.w *= (S); }

// Thread owns all 4 gate rows of element e x cols [12s, 12s+12).
// Weights pre-scaled per gate; SHARED by both sequences (same 48 VGPRs).
#define WLOADPIN(W) \
    const float4* pI = reinterpret_cast<const float4*>((W) + (size_t)e        * HDIM + 12*s); \
    const float4* pF = reinterpret_cast<const float4*>((W) + (size_t)(96 + e) * HDIM + 12*s); \
    const float4* pG = reinterpret_cast<const float4*>((W) + (size_t)(192+ e) * HDIM + 12*s); \
    const float4* pO = reinterpret_cast<const float4*>((W) + (size_t)(288+ e) * HDIM + 12*s); \
    float4 wI0=pI[0], wI1=pI[1], wI2=pI[2]; \
    float4 wF0=pF[0], wF1=pF[1], wF2=pF[2]; \
    float4 wG0=pG[0], wG1=pG[1], wG2=pG[2]; \
    float4 wO0=pO[0], wO1=pO[1], wO2=pO[2]; \
    SC4(wI0,SNEG) SC4(wI1,SNEG) SC4(wI2,SNEG) \
    SC4(wF0,SNEG) SC4(wF1,SNEG) SC4(wF2,SNEG) \
    SC4(wG0,SPOS) SC4(wG1,SPOS) SC4(wG2,SPOS) \
    SC4(wO0,SNEG) SC4(wO1,SNEG) SC4(wO2,SNEG) \
    PIN4x3(wI0,wI1,wI2) PIN4x3(wF0,wF1,wF2) PIN4x3(wG0,wG1,wG2) PIN4x3(wO0,wO1,wO2)

// Suffix-parameterized MV slice (X = A or B), 16 FMAs, ILP-4 per sequence.
#define MVX(n, hv, X) \
  gi##X=fmaf(wI##n.x,hv.x,gi##X); gi##X=fmaf(wI##n.y,hv.y,gi##X); gi##X=fmaf(wI##n.z,hv.z,gi##X); gi##X=fmaf(wI##n.w,hv.w,gi##X); \
  gf##X=fmaf(wF##n.x,hv.x,gf##X); gf##X=fmaf(wF##n.y,hv.y,gf##X); gf##X=fmaf(wF##n.z,hv.z,gf##X); gf##X=fmaf(wF##n.w,hv.w,gf##X); \
  gg##X=fmaf(wG##n.x,hv.x,gg##X); gg##X=fmaf(wG##n.y,hv.y,gg##X); gg##X=fmaf(wG##n.z,hv.z,gg##X); gg##X=fmaf(wG##n.w,hv.w,gg##X); \
  go##X=fmaf(wO##n.x,hv.x,go##X); go##X=fmaf(wO##n.y,hv.y,go##X); go##X=fmaf(wO##n.z,hv.z,go##X); go##X=fmaf(wO##n.w,hv.w,go##X);

// Dual mirror-symmetric transposing-butterfly tail, A/B INTERLEAVED at
// instruction granularity (R10 lesson: waves issue in-order — source-level
// interleave is required for the two chains to overlap). Per-sequence math
// bitwise-identical to R9's verified tail.
#define GT2(STA, STB) \
    float uAA = (tsel & 1) ? gfA : giA,  vAA = (tsel & 1) ? giA : gfA; \
    float uAB = (tsel & 1) ? gfB : giB,  vAB = (tsel & 1) ? giB : gfB; \
    float uBA = (tsel & 1) ? goA : ggA,  vBA = (tsel & 1) ? ggA : goA; \
    float uBB = (tsel & 1) ? goB : ggB,  vBB = (tsel & 1) ? ggB : goB; \
    DPPADDV(uAA, vAA, 0xB1)  DPPADDV(uAB, vAB, 0xB1) \
    DPPADDV(uBA, vBA, 0xB1)  DPPADDV(uBB, vBB, 0xB1) \
    float uCA = (tsel & 2) ? uBA : uAA,  vCA = (tsel & 2) ? uAA : uBA; \
    float uCB = (tsel & 2) ? uBB : uAB,  vCB = (tsel & 2) ? uAB : uBB; \
    DPPADDV(uCA, vCA, 0x4E)  DPPADDV(uCB, vCB, 0x4E) \
    DPPSTEP(uCA, 0x141)      DPPSTEP(uCB, 0x141) \
    float EA = __builtin_amdgcn_exp2f(uCA); \
    float EB = __builtin_amdgcn_exp2f(uCB); \
    float rA = __builtin_amdgcn_rcpf(1.f + EA); \
    float rB = __builtin_amdgcn_rcpf(1.f + EB); \
    int aiA = __float_as_int(fmaf(mC, rA, aC)); \
    int aiB = __float_as_int(fmaf(mC, rB, aC)); \
    QBCAST(siA, aiA, 0x00) QBCAST(siB, aiB, 0x00) \
    QBCAST(sfA, aiA, 0x55) QBCAST(sfB, aiB, 0x55) \
    QBCAST(tgA, aiA, 0xAA) QBCAST(tgB, aiB, 0xAA) \
    QBCAST(soA, aiA, 0xFF) QBCAST(soB, aiB, 0xFF) \
    cUA = fmaf(sfA, cUA, siA * tgA); \
    cUB = fmaf(sfB, cUB, siB * tgB); \
    float eA2 = __builtin_amdgcn_exp2f(SPOS * cUA); \
    float eB2 = __builtin_amdgcn_exp2f(SPOS * cUB); \
    float tA2 = fmaf(-2.f, __builtin_amdgcn_rcpf(1.f + eA2), 1.f); \
    float tB2 = fmaf(-2.f, __builtin_amdgcn_rcpf(1.f + eB2), 1.f); \
    float hNA = soA * tA2; \
    float hNB = soB * tB2; \
    STA STB

// Fused dual LSTM step, role 0. All 6 LDS reads issued up front; MV blocks
// alternate A/B; tails interleaved via GT2.
#define STEP0D(OFF, XTA, XTB) { \
    const float4* hpA = reinterpret_cast<const float4*>(hs2 + (OFF) + 12 * s); \
    const float4* hpB = reinterpret_cast<const float4*>(hs2 + 192 + (OFF) + 12 * s); \
    float4 hA0 = hpA[0], hA1 = hpA[1], hA2 = hpA[2]; \
    float4 hB0 = hpB[0], hB1 = hpB[1], hB2 = hpB[2]; \
    float giA = fmaf(wiI,(XTA),bbI), gfA = fmaf(wiF,(XTA),bbF); \
    float ggA = fmaf(wiG,(XTA),bbG), goA = fmaf(wiO,(XTA),bbO); \
    float giB = fmaf(wiI,(XTB),bbI), gfB = fmaf(wiF,(XTB),bbF); \
    float ggB = fmaf(wiG,(XTB),bbG), goB = fmaf(wiO,(XTB),bbO); \
    MVX(0,hA0,A) MVX(0,hB0,B) MVX(1,hA1,A) MVX(1,hB1,B) MVX(2,hA2,A) MVX(2,hB2,B) \
    GT2( \
      if (w0l) { hs2[((OFF) ^ HDIM) + e] = hNA; *hobpA = hNA; } hobpA += HDIM; , \
      if (w0l) { hs2[192 + ((OFF) ^ HDIM) + e] = hNB; *hobpB = hNB; } hobpB += HDIM; ) }

// Fused dual LSTM step, role 2. xp pre-scaled at role 1.
#define STEP2D(OFF, XPA, XPB) { \
    const float4* hpA = reinterpret_cast<const float4*>(hs2 + (OFF) + 12 * s); \
    const float4* hpB = reinterpret_cast<const float4*>(hs2 + 192 + (OFF) + 12 * s); \
    float4 hA0 = hpA[0], hA1 = hpA[1], hA2 = hpA[2]; \
    float4 hB0 = hpB[0], hB1 = hpB[1], hB2 = hpB[2]; \
    float giA = (XPA).x, gfA = (XPA).y, ggA = (XPA).z, goA = (XPA).w; \
    float giB = (XPB).x, gfB = (XPB).y, ggB = (XPB).z, goB = (XPB).w; \
    MVX(0,hA0,A) MVX(0,hB0,B) MVX(1,hA1,A) MVX(1,hB1,B) MVX(2,hA2,A) MVX(2,hB2,B) \
    GT2( \
      if (w0l) { hs2[((OFF) ^ HDIM) + e] = hNA; *h1pA = hNA; } h1pA += HDIM; , \
      if (w0l) { hs2[192 + ((OFF) ^ HDIM) + e] = hNB; *h1pB = hNB; } h1pB += HDIM; ) }

#define WAIT_GE(PTR, VAL) \
    while (__hip_atomic_load((PTR), __ATOMIC_ACQUIRE, __HIP_MEMORY_SCOPE_AGENT) < (VAL)) \
        __builtin_amdgcn_s_sleep(2);

#define SIGNAL(PTR, VAL) \
    __hip_atomic_store((PTR), (VAL), __ATOMIC_RELEASE, __HIP_MEMORY_SCOPE_AGENT);

__global__ void init_flags(int* flags) {
    if (threadIdx.x < 64) flags[threadIdx.x] = 0;
}

// ---------------------------------------------------------------------------
// 16 blocks, 4 roles x 4 pair-blocks. Pair pr = blockIdx&3 handles batches
// bA=2pr, bB=2pr+1. TWO recurrences per scan block, INTERLEAVED at source
// level so their dependency chains overlap under in-order wave issue.
//   role 0: dual L0 scan -> h0buf, flag0[pr]
//   role 1: xp worker, both batches per chunk -> xp ring, flag1[pr]
//   role 2: dual L1 scan -> h1 ring, flag2[pr]
//   role 3: head, both batches -> out, flag3[pr]
// ---------------------------------------------------------------------------
__global__ void __launch_bounds__(768)
__attribute__((amdgpu_waves_per_eu(3, 3)))
lstm_pipe(const float* __restrict__ x,
          const float* __restrict__ Wih0, const float* __restrict__ Whh0, const float* __restrict__ b0v,
          const float* __restrict__ Wih1, const float* __restrict__ Whh1, const float* __restrict__ b1v,
          const float* __restrict__ h0v,  const float* __restrict__ c0v,
          const float* __restrict__ headw,const float* __restrict__ headb,
          float* __restrict__ h0buf, float* __restrict__ xpbuf, float* __restrict__ h1buf,
          int* flags, float* __restrict__ out)
{
    const int tid  = threadIdx.x;
    const int lane = tid & 63;
    const int e    = tid >> 3;     // element 0..95
    const int s    = tid & 7;      // 12-col segment 0..7
    const bool w0l = ((lane & 7) == 0);

    int* flag0 = flags;
    int* flag1 = flags + 8;
    int* flag2 = flags + 16;
    int* flag3 = flags + 24;

    __shared__ __align__(16) float hs2[2 * 2 * HDIM];   // [seq][dbuf][96]
    __shared__ __align__(16) float h_sh[32 * HDIM];
    __shared__ float ph_sh[2 * G4];          // tt-parity double buffer

    const int role = blockIdx.x >> 2;
    const int pr   = blockIdx.x & 3;
    const int bA   = 2 * pr;
    const int bB   = 2 * pr + 1;

    // mirror-symmetric gate index for the merged butterfly (loop-invariant):
    // quad 0 -> i,f,g,o ; quad 1 -> o,g,f,i
    const int tsel = (s & 3) ^ ((s & 4) ? 3 : 0);
    const float mC = (tsel == 2) ? -2.f : 1.f;
    const float aC = (tsel == 2) ?  1.f : 0.f;

    if (role == 0) {
        // =================== producer: dual L0 scan ===================
        WLOADPIN(Whh0)
        const float wiI = Wih0[e]      * (SNEG * 0.125f);
        const float wiF = Wih0[96 + e] * (SNEG * 0.125f);
        const float wiG = Wih0[192+ e] * (SPOS * 0.125f);
        const float wiO = Wih0[288+ e] * (SNEG * 0.125f);
        const float bbI = b0v[e]       * (SNEG * 0.125f);
        const float bbF = b0v[96 + e]  * (SNEG * 0.125f);
        const float bbG = b0v[192+ e]  * (SPOS * 0.125f);
        const float bbO = b0v[288+ e]  * (SNEG * 0.125f);

        float cUA = c0v[e], cUB = c0v[e];
        if (w0l) { hs2[e] = h0v[e]; hs2[192 + e] = h0v[e]; }
        __syncthreads();

        const float* xbA = x + (size_t)bA * LSEQ;
        const float* xbB = x + (size_t)bB * LSEQ;
        float* hobpA = h0buf + (size_t)bA * LSEQ * HDIM + e;
        float* hobpB = h0buf + (size_t)bB * LSEQ * HDIM + e;

        float4 xAA = *reinterpret_cast<const float4*>(xbA);   // t = 0..3
        float4 xAB = *reinterpret_cast<const float4*>(xbB);

#pragma unroll 1
        for (int gI = 0; gI < LSEQ / 8; ++gI) {
            float4 xBA = *reinterpret_cast<const float4*>(xbA + gI * 8 + 4);
            float4 xBB = *reinterpret_cast<const float4*>(xbB + gI * 8 + 4);
            STEP0D(0,    xAA.x, xAB.x) BARL();
            STEP0D(HDIM, xAA.y, xAB.y) BARL();
            STEP0D(0,    xAA.z, xAB.z) BARL();
            STEP0D(HDIM, xAA.w, xAB.w) BARL();
            const int nOff = ((gI + 1) * 8 < LSEQ) ? (gI + 1) * 8 : LSEQ - 8;
            float4 xAnA = *reinterpret_cast<const float4*>(xbA + nOff);
            float4 xAnB = *reinterpret_cast<const float4*>(xbB + nOff);
            STEP0D(0,    xBA.x, xBB.x) BARL();
            STEP0D(HDIM, xBA.y, xBB.y) BARL();
            STEP0D(0,    xBA.z, xBB.z) BARL();
            STEP0D(HDIM, xBA.w, xBB.w)
            xAA = xAnA; xAB = xAnB;
            if (((gI + 1) & 127) == 0) {      // t+1 = 8(gI+1) ≡ 0 mod TCH
                __threadfence();
                __syncthreads();
                if (tid == 0) SIGNAL(&flag0[pr], (gI + 1) >> 7)
            } else {
                BARL();
            }
        }
    } else if (role == 1) {
        // =================== xp worker (both batches/chunk) ===============
        const bool halfx = (tid >= G4);
        const int  g     = halfx ? tid - G4 : tid;
        const int  dstoff = (g % 96) * 4 + (g / 96);   // (e,gate) float4 layout
        const float gsc  = (((g / 96) == 2) ? SPOS : SNEG) * 0.125f;
        const float4* Wxp = reinterpret_cast<const float4*>(Wih1 + (size_t)g * HDIM + (halfx ? 48 : 0));
        const float xbias = halfx ? 0.f : b1v[g] * gsc;

        float4 q0=Wxp[0],q1=Wxp[1],q2=Wxp[2],q3=Wxp[3],q4=Wxp[4],q5=Wxp[5],
               q6=Wxp[6],q7=Wxp[7],q8=Wxp[8],q9=Wxp[9],q10=Wxp[10],q11=Wxp[11];
        SC4(q0,gsc) SC4(q1,gsc) SC4(q2,gsc)  SC4(q3,gsc) SC4(q4,gsc)  SC4(q5,gsc)
        SC4(q6,gsc) SC4(q7,gsc) SC4(q8,gsc)  SC4(q9,gsc) SC4(q10,gsc) SC4(q11,gsc)
        PIN4x3(q0,q1,q2) PIN4x3(q3,q4,q5) PIN4x3(q6,q7,q8) PIN4x3(q9,q10,q11)

#pragma unroll 1
        for (int k = 0; k < NCH; ++k) {
            if (tid == 0) {
                WAIT_GE(&flag0[pr], k + 1)
                if (k >= 2) WAIT_GE(&flag2[pr], k - 1)
            }
            __syncthreads();
            __threadfence();

#pragma unroll 1
            for (int bb = 0; bb < 2; ++bb) {
                const int b = 2 * pr + bb;
                const float* hsrc = h0buf + (size_t)b * LSEQ * HDIM + (size_t)k * TCH * HDIM;
                float* xpd = xpbuf + ((size_t)b * 2 + (k & 1)) * TCH * G4;

#pragma unroll 1
                for (int t0 = 0; t0 < TCH; t0 += 32) {
                    // 32*96 floats = exactly one float4 per thread
                    reinterpret_cast<float4*>(h_sh)[tid] =
                        reinterpret_cast<const float4*>(hsrc + (size_t)t0 * HDIM)[tid];
                    BARL();
#pragma unroll 1
                    for (int tt = 0; tt < 32; ++tt) {
                        const float4* h4 = reinterpret_cast<const float4*>(
                            h_sh + tt * HDIM + (halfx ? 48 : 0));
                        float a0 = xbias, a1 = 0.f, a2 = 0.f, a3 = 0.f;
                        float4 hv;
                        hv=h4[0];  a0=fmaf(q0.x, hv.x,a0); a1=fmaf(q0.y, hv.y,a1); a2=fmaf(q0.z, hv.z,a2); a3=fmaf(q0.w, hv.w,a3);
                        hv=h4[1];  a0=fmaf(q1.x, hv.x,a0); a1=fmaf(q1.y, hv.y,a1); a2=fmaf(q1.z, hv.z,a2); a3=fmaf(q1.w, hv.w,a3);
                        hv=h4[2];  a0=fmaf(q2.x, hv.x,a0); a1=fmaf(q2.y, hv.y,a1); a2=fmaf(q2.z, hv.z,a2); a3=fmaf(q2.w, hv.w,a3);
                        hv=h4[3];  a0=fmaf(q3.x, hv.x,a0); a1=fmaf(q3.y, hv.y,a1); a2=fmaf(q3.z, hv.z,a2); a3=fmaf(q3.w, hv.w,a3);
                        hv=h4[4];  a0=fmaf(q4.x, hv.x,a0); a1=fmaf(q4.y, hv.y,a1); a2=fmaf(q4.z, hv.z,a2); a3=fmaf(q4.w, hv.w,a3);
                        hv=h4[5];  a0=fmaf(q5.x, hv.x,a0); a1=fmaf(q5.y, hv.y,a1); a2=fmaf(q5.z, hv.z,a2); a3=fmaf(q5.w, hv.w,a3);
                        hv=h4[6];  a0=fmaf(q6.x, hv.x,a0); a1=fmaf(q6.y, hv.y,a1); a2=fmaf(q6.z, hv.z,a2); a3=fmaf(q6.w, hv.w,a3);
                        hv=h4[7];  a0=fmaf(q7.x, hv.x,a0); a1=fmaf(q7.y, hv.y,a1); a2=fmaf(q7.z, hv.z,a2); a3=fmaf(q7.w, hv.w,a3);
                        hv=h4[8];  a0=fmaf(q8.x, hv.x,a0); a1=fmaf(q8.y, hv.y,a1); a2=fmaf(q8.z, hv.z,a2); a3=fmaf(q8.w, hv.w,a3);
                        hv=h4[9];  a0=fmaf(q9.x, hv.x,a0); a1=fmaf(q9.y, hv.y,a1); a2=fmaf(q9.z, hv.z,a2); a3=fmaf(q9.w, hv.w,a3);
                        hv=h4[10]; a0=fmaf(q10.x,hv.x,a0); a1=fmaf(q10.y,hv.y,a1); a2=fmaf(q10.z,hv.z,a2); a3=fmaf(q10.w,hv.w,a3);
                        hv=h4[11]; a0=fmaf(q11.x,hv.x,a0); a1=fmaf(q11.y,hv.y,a1); a2=fmaf(q11.z,hv.z,a2); a3=fmaf(q11.w,hv.w,a3);
                        float part = (a0 + a1) + (a2 + a3);
                        float* ph2 = ph_sh + ((tt & 1) ? G4 : 0);   // parity dbuf
                        if (halfx) ph2[g] = part;
                        BARL();
                        if (!halfx) xpd[(size_t)(t0 + tt) * G4 + dstoff] = part + ph2[g];
                    }
                    BARL();   // protect h_sh + ph slot reuse before next stage
                }
            }
            __threadfence();
            __syncthreads();
            if (tid == 0) SIGNAL(&flag1[pr], k + 1)
        }
    } else if (role == 2) {
        // =================== consumer: dual L1 scan ===================
        WLOADPIN(Whh1)

        float cUA = c0v[HDIM + e], cUB = c0v[HDIM + e];
        if (w0l) { hs2[e] = h0v[HDIM + e]; hs2[192 + e] = h0v[HDIM + e]; }
        __syncthreads();

#pragma unroll 1
        for (int k = 0; k < NCH; ++k) {
            if (tid == 0) {
                WAIT_GE(&flag1[pr], k + 1)
                if (k >= 2) WAIT_GE(&flag3[pr], k - 1)
            }
            __syncthreads();
            __threadfence();

            const float4* xqA = reinterpret_cast<const float4*>(
                xpbuf + ((size_t)bA * 2 + (k & 1)) * TCH * G4) + e;
            const float4* xqB = reinterpret_cast<const float4*>(
                xpbuf + ((size_t)bB * 2 + (k & 1)) * TCH * G4) + e;
            float* h1pA = h1buf + ((size_t)bA * 2 + (k & 1)) * TCH * HDIM + e;
            float* h1pB = h1buf + ((size_t)bB * 2 + (k & 1)) * TCH * HDIM + e;

            float4 aA0 = xqA[0], aA1 = xqA[HDIM], aA2 = xqA[2 * HDIM], aA3 = xqA[3 * HDIM];
            float4 aB0 = xqB[0], aB1 = xqB[HDIM], aB2 = xqB[2 * HDIM], aB3 = xqB[3 * HDIM];

#pragma unroll 1
            for (int gI = 0; gI < TCH / 8; ++gI) {
                const float4* xgA = xqA + (size_t)gI * 8 * HDIM;
                const float4* xgB = xqB + (size_t)gI * 8 * HDIM;
                float4 bA0_, bA1_, bA2_, bA3_, bB0_, bB1_, bB2_, bB3_;
                STEP2D(0,    aA0, aB0) bA0_ = xgA[4 * HDIM]; bB0_ = xgB[4 * HDIM]; BARL();
                STEP2D(HDIM, aA1, aB1) bA1_ = xgA[5 * HDIM]; bB1_ = xgB[5 * HDIM]; BARL();
                STEP2D(0,    aA2, aB2) bA2_ = xgA[6 * HDIM]; bB2_ = xgB[6 * HDIM]; BARL();
                STEP2D(HDIM, aA3, aB3) bA3_ = xgA[7 * HDIM]; bB3_ = xgB[7 * HDIM]; BARL();
                const size_t nO = (size_t)((gI + 1 < TCH / 8) ? (gI + 1) * 8 : TCH - 8) * HDIM;
                const float4* xnA = xqA + nO;
                const float4* xnB = xqB + nO;
                STEP2D(0,    bA0_, bB0_) aA0 = xnA[0];        aB0 = xnB[0];        BARL();
                STEP2D(HDIM, bA1_, bB1_) aA1 = xnA[HDIM];     aB1 = xnB[HDIM];     BARL();
                STEP2D(0,    bA2_, bB2_) aA2 = xnA[2 * HDIM]; aB2 = xnB[2 * HDIM]; BARL();
                STEP2D(HDIM, bA3_, bB3_) aA3 = xnA[3 * HDIM]; aB3 = xnB[3 * HDIM]; BARL();
            }
            __threadfence();
            __syncthreads();
            if (tid == 0) SIGNAL(&flag2[pr], k + 1)
        }
    } else {
        // =================== head (both batches/chunk) ===================
        const float hb = headb[0];
        float4 wv[24];
#pragma unroll
        for (int j = 0; j < 24; ++j) wv[j] = reinterpret_cast<const float4*>(headw)[j];

#pragma unroll 1
        for (int k = 0; k < NCH; ++k) {
            if (tid == 0) WAIT_GE(&flag2[pr], k + 1)
            __syncthreads();
            __threadfence();

#pragma unroll 1
            for (int bb = 0; bb < 2; ++bb) {
                const int b = 2 * pr + bb;
                const float* h1c = h1buf + ((size_t)b * 2 + (k & 1)) * TCH * HDIM;
                for (int t = tid; t < TCH; t += 768) {
                    const float4* hp = reinterpret_cast<const float4*>(h1c + (size_t)t * HDIM);
                    float s2 = 0.f;
#pragma unroll
                    for (int j = 0; j < 24; ++j) {
                        float4 a = hp[j], bwv = wv[j];
                        s2 = fmaf(a.x, bwv.x, s2); s2 = fmaf(a.y, bwv.y, s2);
                        s2 = fmaf(a.z, bwv.z, s2); s2 = fmaf(a.w, bwv.w, s2);
                    }
                    out[(size_t)b * LSEQ + (size_t)k * TCH + t] = s2 + hb;
                }
            }
            __threadfence();
            __syncthreads();
            if (tid == 0) SIGNAL(&flag3[pr], k + 1)
        }
    }
}

// ---------------------------------------------------------------------------
extern "C" void kernel_launch(void* const* d_in, const int* in_sizes, int n_in,
                              void* d_out, int out_size, void* d_ws, size_t ws_size,
                              hipStream_t stream)
{
    const float* x     = (const float*)d_in[0];
    const float* Wih0  = (const float*)d_in[1];
    const float* Whh0  = (const float*)d_in[2];
    const float* b0    = (const float*)d_in[3];
    const float* Wih1  = (const float*)d_in[4];
    const float* Whh1  = (const float*)d_in[5];
    const float* b1    = (const float*)d_in[6];
    const float* h0    = (const float*)d_in[7];
    const float* c0    = (const float*)d_in[8];
    const float* headw = (const float*)d_in[9];
    const float* headb = (const float*)d_in[10];
    float* out = (float*)d_out;

    char* ws = (char*)d_ws;
    const size_t h0bytes = (size_t)BATCH * LSEQ * HDIM * sizeof(float);    // 100.7 MB
    const size_t xpbytes = (size_t)BATCH * 2 * TCH * G4 * sizeof(float);   // 25.2 MB
    const size_t h1bytes = (size_t)BATCH * 2 * TCH * HDIM * sizeof(float); // 6.3 MB

    float* h0buf = (float*)ws;
    float* xpbuf = (float*)(ws + h0bytes);
    float* h1buf = (float*)(ws + h0bytes + xpbytes);
    int*   flags = (int*)  (ws + h0bytes + xpbytes + h1bytes);

    init_flags<<<1, 64, 0, stream>>>(flags);
    lstm_pipe<<<16, 768, 0, stream>>>(x, Wih0, Whh0, b0, Wih1, Whh1, b1,
                                      h0, c0, headw, headb,
                                      h0buf, xpbuf, h1buf, flags, out);
}